// Round 10
// baseline (172.622 us; speedup 1.0000x reference)
//
#include <hip/hip_runtime.h>

#define B_TOTAL 1024
#define NGRID   294912
#define NTILES  (NGRID / 16)          // 18432 n-tiles
#define MARGIN  6e-4f                 // > 2x split-bf16 error bound (~1.2e-4)
#define CAP     (1u << 20)            // candidate buffer entries

#define NBLK2   512                   // mfma blocks (2 per CU, LDS-capped)
#define TPB     (NTILES / NBLK2)      // 36 G-tiles per block
#define TPW2    (TPB / 4)             // 9 G-tiles per wave (36 VGPR af frags)

// ---- ws layout (bytes) ----
#define KEYS_OFF   0u                 // u64 x 1024
#define WSMAX_OFF  8192u              // u32 x 1024 (orderable-uint approx max)
#define CNT_OFF    12288u             // u32 counter
#define CAND_OFF   16384u             // u32 x CAP
#define APACK_OFF  4210688u           // ushort x 1024*32
#define GPACK_OFF  4276224u           // ushort x NGRID*32
#define WS_NEED    23150592u

typedef __attribute__((ext_vector_type(8))) short short8v;
typedef __attribute__((ext_vector_type(4))) float float4v;

__device__ __forceinline__ unsigned short f2bf(float x) {
    unsigned u = __float_as_uint(x);
    unsigned r = ((u >> 16) & 1u) + 0x7FFFu;     // RNE
    return (unsigned short)((u + r) >> 16);
}
__device__ __forceinline__ float bf2f(unsigned short b) {
    return __uint_as_float(((unsigned)b) << 16);
}
__device__ __forceinline__ unsigned ford(float f) {   // order-preserving f32->u32
    unsigned u = __float_as_uint(f);
    return (u & 0x80000000u) ? ~u : (u | 0x80000000u);
}
__device__ __forceinline__ float funord(unsigned u) {
    return __uint_as_float((u & 0x80000000u) ? (u & 0x7FFFFFFFu) : ~u);
}

// ---------------- init ----------------
__global__ __launch_bounds__(256)
void so3_init_kernel(unsigned long long* __restrict__ keys,
                     unsigned* __restrict__ wsmax, unsigned* __restrict__ cnt) {
    int i = blockIdx.x * 256 + threadIdx.x;
    if (i < B_TOTAL) { keys[i] = 0ull; wsmax[i] = 0u; }
    if (i == 0) *cnt = 0u;
}

// ---------------- pack: split-bf16, K=32 slots (verified r8/r9) ----------
// A slots: [0..8]=hi [9..17]=hi [18..26]=lo [27..31]=0
// G slots: [0..8]=hi [9..17]=lo [18..26]=hi [27..31]=0
// dot over slots = hi*hi + hi*lo + lo*hi  (exact minus lo*lo <= ~3.4e-5)
__global__ __launch_bounds__(256)
void so3_pack_kernel(const float* __restrict__ src, unsigned* __restrict__ dst,
                     int nrows, int isA) {
    int id = blockIdx.x * 256 + threadIdx.x;      // one dword (2 slots)
    if (id >= nrows * 16) return;
    int r = id >> 4, i = id & 15;
    unsigned w = 0;
    #pragma unroll
    for (int h = 0; h < 2; ++h) {
        int s = i * 2 + h;
        unsigned short v = 0;
        if (s < 27) {
            int k = (s < 9) ? s : (s < 18 ? s - 9 : s - 18);
            float x = src[(size_t)r * 9 + k];
            unsigned short hi = f2bf(x);
            int wantLo = isA ? (s >= 18) : (s >= 9 && s < 18);
            v = wantLo ? f2bf(x - bf2f(hi)) : hi;
        }
        w |= ((unsigned)v) << (16 * h);
    }
    dst[id] = w;
}

// ---- stage ALL 1024 packed queries -> LDS, XOR-swizzled (verified r8) ----
// Layout: 16B chunk of (row, kb) lives at byte row*64 + (kb^((row>>1)&3))*16.
// Reduces the qt-loop's ds_read_b128 conflicts from 8-way to 2-way (free).
__device__ __forceinline__ void stage_A(const unsigned short* __restrict__ Ap,
                                        unsigned short* sB, int t) {
    #pragma unroll
    for (int i = 0; i < 16; ++i) {
        int id = t + i * 256;                    // 4096 16B-chunks
        int row = id >> 2, kb = id & 3;
        uint4 v = *(const uint4*)(Ap + row * 32 + kb * 8);
        int skb = kb ^ ((row >> 1) & 3);
        *(uint4*)((char*)sB + row * 64 + skb * 16) = v;
    }
}

// ---------------- pass 1: approx max per query ----------------
// Per wave: 9 loop-invariant G A-frags in regs (each G byte read ONCE
// chip-wide), sweep 64 query-tiles from LDS. Per qt: 1 ds_read_b128 +
// 9 MFMA + max3 chain + shfl reduce + pre-checked atomicMax. State = 1 reg.
// C layout (verified r8): col=lane&15=query, row=(lane>>4)*4+reg=grid row.
__global__ __launch_bounds__(256, 2)
void so3_mfma_max_kernel(const unsigned short* __restrict__ Ap,
                         const unsigned short* __restrict__ Gp,
                         unsigned* __restrict__ wsmax) {
    __shared__ __align__(16) unsigned short sB[1024 * 32];   // 64 KB
    const int t = threadIdx.x, l = t & 63, w = t >> 6;
    const int lr = l & 15, lk = l >> 4;

    stage_A(Ap, sB, t);

    const int tile0 = blockIdx.x * TPB + w * TPW2;
    short8v af[TPW2];                              // 36 VGPR, loaded once
    #pragma unroll
    for (int i = 0; i < TPW2; ++i)
        af[i] = *(const short8v*)(Gp + (size_t)((tile0 + i) * 16 + lr) * 32 + lk * 8);

    __syncthreads();

    for (int qt = 0; qt < 64; ++qt) {
        const int row = qt * 16 + lr;
        const int skb = lk ^ ((row >> 1) & 3);
        short8v bf = *(const short8v*)((const char*)sB + row * 64 + skb * 16);
        float m = -1e30f;
        #pragma unroll
        for (int i = 0; i < TPW2; ++i) {
            float4v c = {0.f, 0.f, 0.f, 0.f};
            c = __builtin_amdgcn_mfma_f32_16x16x32_bf16(af[i], bf, c, 0, 0, 0);
            float m3 = fmaxf(fmaxf(c[0], c[1]), c[2]);     // v_max3
            m = fmaxf(fmaxf(m3, c[3]), m);                 // v_max3
        }
        // lanes sharing (l&15) hold same query: reduce over lk
        m = fmaxf(m, __shfl_xor(m, 16));
        m = fmaxf(m, __shfl_xor(m, 32));
        if (l < 16) {
            unsigned u = ford(m);
            unsigned* p = wsmax + qt * 16 + l;
            if (u > *p) atomicMax(p, u);   // monotone: stale read only under-reads
        }
    }
}

// ---------------- pass 2: emit candidates >= max - MARGIN ----------------
__global__ __launch_bounds__(256, 2)
void so3_mfma_cand_kernel(const unsigned short* __restrict__ Ap,
                          const unsigned short* __restrict__ Gp,
                          const unsigned* __restrict__ wsmax,
                          unsigned* __restrict__ cnt,
                          unsigned* __restrict__ cands) {
    __shared__ __align__(16) unsigned short sB[1024 * 32];
    const int t = threadIdx.x, l = t & 63, w = t >> 6;
    const int lr = l & 15, lk = l >> 4;

    stage_A(Ap, sB, t);

    const int tile0 = blockIdx.x * TPB + w * TPW2;
    short8v af[TPW2];
    #pragma unroll
    for (int i = 0; i < TPW2; ++i)
        af[i] = *(const short8v*)(Gp + (size_t)((tile0 + i) * 16 + lr) * 32 + lk * 8);

    __syncthreads();

    for (int qt = 0; qt < 64; ++qt) {
        const int row = qt * 16 + lr;                 // this lane's query
        const float thr = funord(wsmax[row]) - MARGIN;
        const int skb = lk ^ ((row >> 1) & 3);
        short8v bf = *(const short8v*)((const char*)sB + row * 64 + skb * 16);
        #pragma unroll
        for (int i = 0; i < TPW2; ++i) {
            float4v c = {0.f, 0.f, 0.f, 0.f};
            c = __builtin_amdgcn_mfma_f32_16x16x32_bf16(af[i], bf, c, 0, 0, 0);
            float m4 = fmaxf(fmaxf(fmaxf(c[0], c[1]), c[2]), c[3]);
            if (m4 >= thr) {                          // rare slow path
                #pragma unroll
                for (int r = 0; r < 4; ++r) {
                    if (c[r] >= thr) {
                        int n = (tile0 + i) * 16 + lk * 4 + r;
                        unsigned idx = atomicAdd(cnt, 1u);
                        if (idx < CAP)
                            cands[idx] = ((unsigned)row << 19) | (unsigned)n;
                    }
                }
            }
        }
    }
}

// ---------------- pass 3: exact fp32 rescore of candidates ----------------
__global__ __launch_bounds__(256)
void so3_rescore_kernel(const float* __restrict__ A, const float* __restrict__ G,
                        const unsigned* __restrict__ cnt,
                        const unsigned* __restrict__ cands,
                        unsigned long long* __restrict__ keys) {
    unsigned total = *cnt;
    if (total > CAP) total = CAP;
    const unsigned stride = gridDim.x * 256;
    for (unsigned i = blockIdx.x * 256 + threadIdx.x; i < total; i += stride) {
        unsigned cd = cands[i];
        int b = (int)(cd >> 19), n = (int)(cd & 0x7FFFFu);
        const float* a = A + (size_t)b * 9;
        const float* g = G + (size_t)n * 9;
        // EXACT chain — identical order to reference-matching rounds 2..9
        float d;
        d = a[0] * g[0];
        d = fmaf(a[1], g[1], d);
        d = fmaf(a[2], g[2], d);
        d = fmaf(a[3], g[3], d);
        d = fmaf(a[4], g[4], d);
        d = fmaf(a[5], g[5], d);
        d = fmaf(a[6], g[6], d);
        d = fmaf(a[7], g[7], d);
        d = fmaf(a[8], g[8], d);
        unsigned long long key =
            ((unsigned long long)ford(d) << 32) | (unsigned)(~n);
        unsigned long long seen = keys[b];
        if (key > seen) atomicMax(&keys[b], key);
    }
}

// ---------------- final: unpack + gather ----------------
__global__ __launch_bounds__(256)
void so3_final_kernel(const float* __restrict__ G,
                      const unsigned long long* __restrict__ keys,
                      float* __restrict__ out) {
    int b = blockIdx.x * 256 + threadIdx.x;
    if (b >= B_TOTAL) return;
    unsigned long long key = keys[b];
    unsigned hi = (unsigned)(key >> 32);
    int idx = (int)(~(unsigned)key);
    out[b] = funord(hi);
    const float* g = G + (size_t)idx * 9;
    float* o = out + B_TOTAL + (size_t)b * 9;
    #pragma unroll
    for (int k = 0; k < 9; ++k) o[k] = g[k];
}

// ---------------- fallback (round-5 VALU path, 85.9 us known-good) --------
#define FB_NBLK  2048
#define FB_CHUNK (NGRID / FB_NBLK)
#define FB_NTHR  128
#define FB_BPT   8
__global__ __launch_bounds__(FB_NTHR, 4)
void so3_fb_partial_kernel(const float* __restrict__ A, const float* __restrict__ G,
                           unsigned long long* __restrict__ ws) {
    __shared__ __align__(16) float sG[FB_CHUNK * 12];
    const int t = threadIdx.x;
    const int n0 = blockIdx.x * FB_CHUNK;
    for (int i = t; i < FB_CHUNK * 9; i += FB_NTHR) {
        int row = i / 9, k = i - row * 9;
        sG[row * 12 + k] = G[(size_t)n0 * 9 + i];
    }
    float a[FB_BPT][9];
    #pragma unroll
    for (int j = 0; j < FB_BPT; ++j) {
        const float* ap = A + (size_t)(j * FB_NTHR + t) * 9;
        #pragma unroll
        for (int k = 0; k < 9; ++k) a[j][k] = ap[k];
    }
    float best[FB_BPT]; int bidx[FB_BPT];
    #pragma unroll
    for (int j = 0; j < FB_BPT; ++j) { best[j] = -1e30f; bidx[j] = 0; }
    __syncthreads();
    #pragma unroll 2
    for (int n = 0; n < FB_CHUNK; ++n) {
        const float4* gv = (const float4*)(sG + n * 12);
        const float4 gA = gv[0], gB = gv[1];
        const float g8 = sG[n * 12 + 8];
        const int vn = n0 + n;
        #pragma unroll
        for (int j = 0; j < FB_BPT; ++j) {
            float d;
            d = a[j][0] * gA.x; d = fmaf(a[j][1], gA.y, d); d = fmaf(a[j][2], gA.z, d);
            d = fmaf(a[j][3], gA.w, d); d = fmaf(a[j][4], gB.x, d); d = fmaf(a[j][5], gB.y, d);
            d = fmaf(a[j][6], gB.z, d); d = fmaf(a[j][7], gB.w, d); d = fmaf(a[j][8], g8, d);
            if (d > best[j]) { best[j] = d; bidx[j] = vn; }
        }
    }
    #pragma unroll
    for (int j = 0; j < FB_BPT; ++j) {
        unsigned long long key =
            ((unsigned long long)ford(best[j]) << 32) | (unsigned)(~bidx[j]);
        unsigned long long seen = ws[j * FB_NTHR + t];
        if (key > seen) atomicMax(&ws[j * FB_NTHR + t], key);
    }
}

extern "C" void kernel_launch(void* const* d_in, const int* in_sizes, int n_in,
                              void* d_out, int out_size, void* d_ws, size_t ws_size,
                              hipStream_t stream) {
    const float* A = (const float*)d_in[0];   // rotMat [1024,3,3] fp32
    const float* G = (const float*)d_in[1];   // output_rotmats [294912,3,3] fp32
    float* out = (float*)d_out;
    char* ws = (char*)d_ws;
    unsigned long long* keys = (unsigned long long*)(ws + KEYS_OFF);
    unsigned* wsmax = (unsigned*)(ws + WSMAX_OFF);
    unsigned* cnt   = (unsigned*)(ws + CNT_OFF);
    unsigned* cands = (unsigned*)(ws + CAND_OFF);
    unsigned short* Ap = (unsigned short*)(ws + APACK_OFF);
    unsigned short* Gp = (unsigned short*)(ws + GPACK_OFF);

    if (ws_size < WS_NEED) {   // defensive: unknown ws budget -> proven VALU path
        hipLaunchKernelGGL(so3_init_kernel, dim3(4), dim3(256), 0, stream,
                           keys, wsmax, cnt);
        hipLaunchKernelGGL(so3_fb_partial_kernel, dim3(FB_NBLK), dim3(FB_NTHR),
                           0, stream, A, G, keys);
        hipLaunchKernelGGL(so3_final_kernel, dim3(4), dim3(256), 0, stream,
                           G, keys, out);
        return;
    }

    hipLaunchKernelGGL(so3_init_kernel, dim3(4), dim3(256), 0, stream,
                       keys, wsmax, cnt);
    hipLaunchKernelGGL(so3_pack_kernel, dim3((B_TOTAL * 16) / 256), dim3(256),
                       0, stream, A, (unsigned*)Ap, B_TOTAL, 1);
    hipLaunchKernelGGL(so3_pack_kernel, dim3((NGRID * 16) / 256), dim3(256),
                       0, stream, G, (unsigned*)Gp, NGRID, 0);
    hipLaunchKernelGGL(so3_mfma_max_kernel, dim3(NBLK2), dim3(256), 0, stream,
                       Ap, Gp, wsmax);
    hipLaunchKernelGGL(so3_mfma_cand_kernel, dim3(NBLK2), dim3(256), 0, stream,
                       Ap, Gp, wsmax, cnt, cands);
    hipLaunchKernelGGL(so3_rescore_kernel, dim3(64), dim3(256), 0, stream,
                       A, G, cnt, cands, keys);
    hipLaunchKernelGGL(so3_final_kernel, dim3(4), dim3(256), 0, stream,
                       G, keys, out);
}

// Round 11
// 103.151 us; speedup vs baseline: 1.6735x; 1.6735x over previous
//
#include <hip/hip_runtime.h>

#define B_TOTAL 1024
#define NGRID   294912
#define NTILES  (NGRID / 16)          // 18432 n-tiles
#define MARGIN  6e-4f                 // > 2x split-bf16 error bound (~1.2e-4)
#define CAP     (1u << 20)            // candidate buffer entries

#define NBLK2   512                   // mfma blocks (2 per CU, LDS-capped)
#define TPB     (NTILES / NBLK2)      // 36 G-tiles per block
#define TPW2    (TPB / 4)             // 9 G-tiles per wave (36 VGPR af frags)

// ---- ws layout (bytes) ----
#define KEYS_OFF   0u                 // u64 x 1024
#define WSMAX_OFF  8192u              // u32 x 1024 (orderable-uint approx max)
#define CNT_OFF    12288u             // u32 counter
#define CAND_OFF   16384u             // u32 x CAP
#define APACK_OFF  4210688u           // ushort x 1024*32
#define GPACK_OFF  4276224u           // ushort x NGRID*32
#define WS_NEED    23150592u

typedef __attribute__((ext_vector_type(8))) short short8v;
typedef __attribute__((ext_vector_type(4))) float float4v;

__device__ __forceinline__ unsigned short f2bf(float x) {
    unsigned u = __float_as_uint(x);
    unsigned r = ((u >> 16) & 1u) + 0x7FFFu;     // RNE
    return (unsigned short)((u + r) >> 16);
}
__device__ __forceinline__ float bf2f(unsigned short b) {
    return __uint_as_float(((unsigned)b) << 16);
}
__device__ __forceinline__ unsigned ford(float f) {   // order-preserving f32->u32
    unsigned u = __float_as_uint(f);
    return (u & 0x80000000u) ? ~u : (u | 0x80000000u);
}
__device__ __forceinline__ float funord(unsigned u) {
    return __uint_as_float((u & 0x80000000u) ? (u & 0x7FFFFFFFu) : ~u);
}

// ---------------- init ----------------
__global__ __launch_bounds__(256)
void so3_init_kernel(unsigned long long* __restrict__ keys,
                     unsigned* __restrict__ wsmax, unsigned* __restrict__ cnt) {
    int i = blockIdx.x * 256 + threadIdx.x;
    if (i < B_TOTAL) { keys[i] = 0ull; wsmax[i] = 0u; }
    if (i == 0) *cnt = 0u;
}

// ---------------- pack: split-bf16, K=32 slots (verified r8-r10) ---------
// A slots: [0..8]=hi [9..17]=hi [18..26]=lo [27..31]=0
// G slots: [0..8]=hi [9..17]=lo [18..26]=hi [27..31]=0
// dot over slots = hi*hi + hi*lo + lo*hi  (exact minus lo*lo <= ~3.4e-5)
__global__ __launch_bounds__(256)
void so3_pack_kernel(const float* __restrict__ src, unsigned* __restrict__ dst,
                     int nrows, int isA) {
    int id = blockIdx.x * 256 + threadIdx.x;      // one dword (2 slots)
    if (id >= nrows * 16) return;
    int r = id >> 4, i = id & 15;
    unsigned w = 0;
    #pragma unroll
    for (int h = 0; h < 2; ++h) {
        int s = i * 2 + h;
        unsigned short v = 0;
        if (s < 27) {
            int k = (s < 9) ? s : (s < 18 ? s - 9 : s - 18);
            float x = src[(size_t)r * 9 + k];
            unsigned short hi = f2bf(x);
            int wantLo = isA ? (s >= 18) : (s >= 9 && s < 18);
            v = wantLo ? f2bf(x - bf2f(hi)) : hi;
        }
        w |= ((unsigned)v) << (16 * h);
    }
    dst[id] = w;
}

// ---- stage ALL 1024 packed queries -> LDS, XOR-swizzled (verified r8) ----
__device__ __forceinline__ void stage_A(const unsigned short* __restrict__ Ap,
                                        unsigned short* sB, int t) {
    #pragma unroll
    for (int i = 0; i < 16; ++i) {
        int id = t + i * 256;                    // 4096 16B-chunks
        int row = id >> 2, kb = id & 3;
        uint4 v = *(const uint4*)(Ap + row * 32 + kb * 8);
        int skb = kb ^ ((row >> 1) & 3);
        *(uint4*)((char*)sB + row * 64 + skb * 16) = v;
    }
}

// ---------------- pass 1: approx max per query ----------------
// r10 lesson: NO global reads/atomics inside the qt loop (each was a
// serialized cross-XCD round-trip gating a branch). Inner loop touches only
// registers + LDS; per-wave maxima go to sW; ONE pre-checked atomic flush
// per (query) per block at the end.
__global__ __launch_bounds__(256, 2)
void so3_mfma_max_kernel(const unsigned short* __restrict__ Ap,
                         const unsigned short* __restrict__ Gp,
                         unsigned* __restrict__ wsmax) {
    __shared__ __align__(16) unsigned short sB[1024 * 32];   // 64 KB
    __shared__ float sW[4][64][16];                          // 16 KB (80 total)
    const int t = threadIdx.x, l = t & 63, w = t >> 6;
    const int lr = l & 15, lk = l >> 4;

    stage_A(Ap, sB, t);

    const int tile0 = blockIdx.x * TPB + w * TPW2;
    short8v af[TPW2];                              // 36 VGPR, loaded once
    #pragma unroll
    for (int i = 0; i < TPW2; ++i)
        af[i] = *(const short8v*)(Gp + (size_t)((tile0 + i) * 16 + lr) * 32 + lk * 8);

    __syncthreads();

    for (int qt = 0; qt < 64; ++qt) {
        const int row = qt * 16 + lr;
        const int skb = lk ^ ((row >> 1) & 3);
        short8v bf = *(const short8v*)((const char*)sB + row * 64 + skb * 16);
        float m = -1e30f;
        #pragma unroll
        for (int i = 0; i < TPW2; ++i) {
            float4v c = {0.f, 0.f, 0.f, 0.f};
            c = __builtin_amdgcn_mfma_f32_16x16x32_bf16(af[i], bf, c, 0, 0, 0);
            float m3 = fmaxf(fmaxf(c[0], c[1]), c[2]);     // v_max3
            m = fmaxf(fmaxf(m3, c[3]), m);                 // v_max3
        }
        // lanes sharing (l&15) hold same query: reduce over lk (reg/LDS only)
        m = fmaxf(m, __shfl_xor(m, 16));
        m = fmaxf(m, __shfl_xor(m, 32));
        if (l < 16) sW[w][qt][l] = m;      // lane-id branch: no memory wait
    }
    __syncthreads();

    // Post-loop flush: block-level 4-wave reduce + pre-checked atomicMax.
    for (int e = t; e < 1024; e += 256) {
        int qt = e >> 4, q = e & 15;
        float v = fmaxf(fmaxf(sW[0][qt][q], sW[1][qt][q]),
                        fmaxf(sW[2][qt][q], sW[3][qt][q]));
        unsigned u = ford(v);
        unsigned* p = wsmax + e;
        if (u > *p) atomicMax(p, u);   // monotone: stale read only over-admits
    }
}

// ---------------- pass 2: emit candidates >= max - MARGIN ----------------
__global__ __launch_bounds__(256, 2)
void so3_mfma_cand_kernel(const unsigned short* __restrict__ Ap,
                          const unsigned short* __restrict__ Gp,
                          const unsigned* __restrict__ wsmax,
                          unsigned* __restrict__ cnt,
                          unsigned* __restrict__ cands) {
    __shared__ __align__(16) unsigned short sB[1024 * 32];   // 64 KB
    __shared__ float sThr[1024];                             // 4 KB
    const int t = threadIdx.x, l = t & 63, w = t >> 6;
    const int lr = l & 15, lk = l >> 4;

    stage_A(Ap, sB, t);
    for (int e = t; e < 1024; e += 256)        // thresholds -> LDS, ONCE
        sThr[e] = funord(wsmax[e]) - MARGIN;

    const int tile0 = blockIdx.x * TPB + w * TPW2;
    short8v af[TPW2];
    #pragma unroll
    for (int i = 0; i < TPW2; ++i)
        af[i] = *(const short8v*)(Gp + (size_t)((tile0 + i) * 16 + lr) * 32 + lk * 8);

    __syncthreads();

    for (int qt = 0; qt < 64; ++qt) {
        const int row = qt * 16 + lr;                 // this lane's query
        const float thr = sThr[row];                  // LDS read, uncontended
        const int skb = lk ^ ((row >> 1) & 3);
        short8v bf = *(const short8v*)((const char*)sB + row * 64 + skb * 16);
        #pragma unroll
        for (int i = 0; i < TPW2; ++i) {
            float4v c = {0.f, 0.f, 0.f, 0.f};
            c = __builtin_amdgcn_mfma_f32_16x16x32_bf16(af[i], bf, c, 0, 0, 0);
            float m4 = fmaxf(fmaxf(fmaxf(c[0], c[1]), c[2]), c[3]);
            if (m4 >= thr) {                          // rare slow path
                #pragma unroll
                for (int r = 0; r < 4; ++r) {
                    if (c[r] >= thr) {
                        int n = (tile0 + i) * 16 + lk * 4 + r;
                        unsigned idx = atomicAdd(cnt, 1u);
                        if (idx < CAP)
                            cands[idx] = ((unsigned)row << 19) | (unsigned)n;
                    }
                }
            }
        }
    }
}

// ---------------- pass 3: exact fp32 rescore of candidates ----------------
__global__ __launch_bounds__(256)
void so3_rescore_kernel(const float* __restrict__ A, const float* __restrict__ G,
                        const unsigned* __restrict__ cnt,
                        const unsigned* __restrict__ cands,
                        unsigned long long* __restrict__ keys) {
    unsigned total = *cnt;
    if (total > CAP) total = CAP;
    const unsigned stride = gridDim.x * 256;
    for (unsigned i = blockIdx.x * 256 + threadIdx.x; i < total; i += stride) {
        unsigned cd = cands[i];
        int b = (int)(cd >> 19), n = (int)(cd & 0x7FFFFu);
        const float* a = A + (size_t)b * 9;
        const float* g = G + (size_t)n * 9;
        // EXACT chain — identical order to reference-matching rounds 2..10
        float d;
        d = a[0] * g[0];
        d = fmaf(a[1], g[1], d);
        d = fmaf(a[2], g[2], d);
        d = fmaf(a[3], g[3], d);
        d = fmaf(a[4], g[4], d);
        d = fmaf(a[5], g[5], d);
        d = fmaf(a[6], g[6], d);
        d = fmaf(a[7], g[7], d);
        d = fmaf(a[8], g[8], d);
        unsigned long long key =
            ((unsigned long long)ford(d) << 32) | (unsigned)(~n);
        unsigned long long seen = keys[b];
        if (key > seen) atomicMax(&keys[b], key);
    }
}

// ---------------- final: unpack + gather ----------------
__global__ __launch_bounds__(256)
void so3_final_kernel(const float* __restrict__ G,
                      const unsigned long long* __restrict__ keys,
                      float* __restrict__ out) {
    int b = blockIdx.x * 256 + threadIdx.x;
    if (b >= B_TOTAL) return;
    unsigned long long key = keys[b];
    unsigned hi = (unsigned)(key >> 32);
    int idx = (int)(~(unsigned)key);
    out[b] = funord(hi);
    const float* g = G + (size_t)idx * 9;
    float* o = out + B_TOTAL + (size_t)b * 9;
    #pragma unroll
    for (int k = 0; k < 9; ++k) o[k] = g[k];
}

// ---------------- fallback (round-5 VALU path, 85.9 us known-good) --------
#define FB_NBLK  2048
#define FB_CHUNK (NGRID / FB_NBLK)
#define FB_NTHR  128
#define FB_BPT   8
__global__ __launch_bounds__(FB_NTHR, 4)
void so3_fb_partial_kernel(const float* __restrict__ A, const float* __restrict__ G,
                           unsigned long long* __restrict__ ws) {
    __shared__ __align__(16) float sG[FB_CHUNK * 12];
    const int t = threadIdx.x;
    const int n0 = blockIdx.x * FB_CHUNK;
    for (int i = t; i < FB_CHUNK * 9; i += FB_NTHR) {
        int row = i / 9, k = i - row * 9;
        sG[row * 12 + k] = G[(size_t)n0 * 9 + i];
    }
    float a[FB_BPT][9];
    #pragma unroll
    for (int j = 0; j < FB_BPT; ++j) {
        const float* ap = A + (size_t)(j * FB_NTHR + t) * 9;
        #pragma unroll
        for (int k = 0; k < 9; ++k) a[j][k] = ap[k];
    }
    float best[FB_BPT]; int bidx[FB_BPT];
    #pragma unroll
    for (int j = 0; j < FB_BPT; ++j) { best[j] = -1e30f; bidx[j] = 0; }
    __syncthreads();
    #pragma unroll 2
    for (int n = 0; n < FB_CHUNK; ++n) {
        const float4* gv = (const float4*)(sG + n * 12);
        const float4 gA = gv[0], gB = gv[1];
        const float g8 = sG[n * 12 + 8];
        const int vn = n0 + n;
        #pragma unroll
        for (int j = 0; j < FB_BPT; ++j) {
            float d;
            d = a[j][0] * gA.x; d = fmaf(a[j][1], gA.y, d); d = fmaf(a[j][2], gA.z, d);
            d = fmaf(a[j][3], gA.w, d); d = fmaf(a[j][4], gB.x, d); d = fmaf(a[j][5], gB.y, d);
            d = fmaf(a[j][6], gB.z, d); d = fmaf(a[j][7], gB.w, d); d = fmaf(a[j][8], g8, d);
            if (d > best[j]) { best[j] = d; bidx[j] = vn; }
        }
    }
    #pragma unroll
    for (int j = 0; j < FB_BPT; ++j) {
        unsigned long long key =
            ((unsigned long long)ford(best[j]) << 32) | (unsigned)(~bidx[j]);
        unsigned long long seen = ws[j * FB_NTHR + t];
        if (key > seen) atomicMax(&ws[j * FB_NTHR + t], key);
    }
}

extern "C" void kernel_launch(void* const* d_in, const int* in_sizes, int n_in,
                              void* d_out, int out_size, void* d_ws, size_t ws_size,
                              hipStream_t stream) {
    const float* A = (const float*)d_in[0];   // rotMat [1024,3,3] fp32
    const float* G = (const float*)d_in[1];   // output_rotmats [294912,3,3] fp32
    float* out = (float*)d_out;
    char* ws = (char*)d_ws;
    unsigned long long* keys = (unsigned long long*)(ws + KEYS_OFF);
    unsigned* wsmax = (unsigned*)(ws + WSMAX_OFF);
    unsigned* cnt   = (unsigned*)(ws + CNT_OFF);
    unsigned* cands = (unsigned*)(ws + CAND_OFF);
    unsigned short* Ap = (unsigned short*)(ws + APACK_OFF);
    unsigned short* Gp = (unsigned short*)(ws + GPACK_OFF);

    if (ws_size < WS_NEED) {   // defensive: unknown ws budget -> proven VALU path
        hipLaunchKernelGGL(so3_init_kernel, dim3(4), dim3(256), 0, stream,
                           keys, wsmax, cnt);
        hipLaunchKernelGGL(so3_fb_partial_kernel, dim3(FB_NBLK), dim3(FB_NTHR),
                           0, stream, A, G, keys);
        hipLaunchKernelGGL(so3_final_kernel, dim3(4), dim3(256), 0, stream,
                           G, keys, out);
        return;
    }

    hipLaunchKernelGGL(so3_init_kernel, dim3(4), dim3(256), 0, stream,
                       keys, wsmax, cnt);
    hipLaunchKernelGGL(so3_pack_kernel, dim3((B_TOTAL * 16) / 256), dim3(256),
                       0, stream, A, (unsigned*)Ap, B_TOTAL, 1);
    hipLaunchKernelGGL(so3_pack_kernel, dim3((NGRID * 16) / 256), dim3(256),
                       0, stream, G, (unsigned*)Gp, NGRID, 0);
    hipLaunchKernelGGL(so3_mfma_max_kernel, dim3(NBLK2), dim3(256), 0, stream,
                       Ap, Gp, wsmax);
    hipLaunchKernelGGL(so3_mfma_cand_kernel, dim3(NBLK2), dim3(256), 0, stream,
                       Ap, Gp, wsmax, cnt, cands);
    hipLaunchKernelGGL(so3_rescore_kernel, dim3(128), dim3(256), 0, stream,
                       A, G, cnt, cands, keys);
    hipLaunchKernelGGL(so3_final_kernel, dim3(4), dim3(256), 0, stream,
                       G, keys, out);
}

// Round 12
// 87.903 us; speedup vs baseline: 1.9638x; 1.1735x over previous
//
#include <hip/hip_runtime.h>

#define B_TOTAL 1024
#define NGRID   294912
#define NTILES  (NGRID / 16)          // 18432 n-tiles
#define MARGIN  6e-4f                 // > 2x split-bf16 error bound (~1.2e-4)
#define CAP     (1u << 20)            // candidate buffer entries

#define QBLK    256                   // queries per block (16 KB LDS)
#define QTILES  (QBLK / 16)           // 16 query-tiles per block
#define NSLICE  512                   // tile slices
#define TPB     (NTILES / NSLICE)     // 36 G-tiles per slice
#define TPW2    (TPB / 4)             // 9 G-tiles per wave (36 VGPR af frags)

// ---- ws layout (bytes) ----
#define KEYS_OFF   0u                 // u64 x 1024
#define WSMAX_OFF  8192u              // u32 x 1024 (orderable-uint approx max)
#define CNT_OFF    12288u             // u32 counter
#define CAND_OFF   16384u             // u32 x CAP
#define APACK_OFF  4210688u           // ushort x 1024*32
#define GPACK_OFF  4276224u           // ushort x NGRID*32
#define WS_NEED    23150592u

typedef __attribute__((ext_vector_type(8))) short short8v;
typedef __attribute__((ext_vector_type(4))) float float4v;

__device__ __forceinline__ unsigned short f2bf(float x) {
    unsigned u = __float_as_uint(x);
    unsigned r = ((u >> 16) & 1u) + 0x7FFFu;     // RNE
    return (unsigned short)((u + r) >> 16);
}
__device__ __forceinline__ float bf2f(unsigned short b) {
    return __uint_as_float(((unsigned)b) << 16);
}
__device__ __forceinline__ unsigned ford(float f) {   // order-preserving f32->u32
    unsigned u = __float_as_uint(f);
    return (u & 0x80000000u) ? ~u : (u | 0x80000000u);
}
__device__ __forceinline__ float funord(unsigned u) {
    return __uint_as_float((u & 0x80000000u) ? (u & 0x7FFFFFFFu) : ~u);
}

// ---------------- init ----------------
__global__ __launch_bounds__(256)
void so3_init_kernel(unsigned long long* __restrict__ keys,
                     unsigned* __restrict__ wsmax, unsigned* __restrict__ cnt) {
    int i = blockIdx.x * 256 + threadIdx.x;
    if (i < B_TOTAL) { keys[i] = 0ull; wsmax[i] = 0u; }
    if (i == 0) *cnt = 0u;
}

// ---------------- pack: split-bf16, K=32 slots (verified r8-r11) ---------
// A slots: [0..8]=hi [9..17]=hi [18..26]=lo [27..31]=0
// G slots: [0..8]=hi [9..17]=lo [18..26]=hi [27..31]=0
// dot over slots = hi*hi + hi*lo + lo*hi  (exact minus lo*lo <= ~3.4e-5)
__global__ __launch_bounds__(256)
void so3_pack_kernel(const float* __restrict__ src, unsigned* __restrict__ dst,
                     int nrows, int isA) {
    int id = blockIdx.x * 256 + threadIdx.x;      // one dword (2 slots)
    if (id >= nrows * 16) return;
    int r = id >> 4, i = id & 15;
    unsigned w = 0;
    #pragma unroll
    for (int h = 0; h < 2; ++h) {
        int s = i * 2 + h;
        unsigned short v = 0;
        if (s < 27) {
            int k = (s < 9) ? s : (s < 18 ? s - 9 : s - 18);
            float x = src[(size_t)r * 9 + k];
            unsigned short hi = f2bf(x);
            int wantLo = isA ? (s >= 18) : (s >= 9 && s < 18);
            v = wantLo ? f2bf(x - bf2f(hi)) : hi;
        }
        w |= ((unsigned)v) << (16 * h);
    }
    dst[id] = w;
}

// ---- stage QBLK packed queries -> LDS, XOR-swizzled (verified r8) -------
__device__ __forceinline__ void stage_A(const unsigned short* __restrict__ Ap,
                                        unsigned short* sB, int t, int qbase) {
    #pragma unroll
    for (int i = 0; i < QBLK / 64; ++i) {        // 1024 16B-chunks, 4/thread
        int id = t + i * 256;
        int row = id >> 2, kb = id & 3;
        uint4 v = *(const uint4*)(Ap + (size_t)(qbase + row) * 32 + kb * 8);
        int skb = kb ^ ((row >> 1) & 3);
        *(uint4*)((char*)sB + row * 64 + skb * 16) = v;
    }
}

// 9 c-maxes -> 1, as a shallow tree (independent pairs, then max3).
__device__ __forceinline__ float tree_max9(const float* m4) {
    float a = fmaxf(fmaxf(m4[0], m4[1]), m4[2]);
    float b = fmaxf(fmaxf(m4[3], m4[4]), m4[5]);
    float c = fmaxf(fmaxf(m4[6], m4[7]), m4[8]);
    return fmaxf(fmaxf(a, b), c);
}

// ---------------- pass 1: approx max per query ----------------
// Inner loop touches only regs + LDS (r10/r11 lesson). Per qt:
// 1 ds_read_b128 + 9 MFMA + tree-max + 1 coalesced ds_write. No shfl
// (r11 lesson: 2x ds_bpermute latency per qt dominated the tail) —
// per-lk partials land in sW, reduced once at flush.
__global__ __launch_bounds__(256, 4)
void so3_mfma_max_kernel(const unsigned short* __restrict__ Ap,
                         const unsigned short* __restrict__ Gp,
                         unsigned* __restrict__ wsmax) {
    __shared__ __align__(16) unsigned short sB[QBLK * 32];   // 16 KB
    __shared__ float sW[4][QTILES][4][16];                   // 16 KB
    const int t = threadIdx.x, l = t & 63, w = t >> 6;
    const int lr = l & 15, lk = l >> 4;
    const int qbase = blockIdx.y * QBLK;

    stage_A(Ap, sB, t, qbase);

    const int tile0 = blockIdx.x * TPB + w * TPW2;
    short8v af[TPW2];                              // 36 VGPR, loaded once
    #pragma unroll
    for (int i = 0; i < TPW2; ++i)
        af[i] = *(const short8v*)(Gp + (size_t)((tile0 + i) * 16 + lr) * 32 + lk * 8);

    __syncthreads();

    for (int qt = 0; qt < QTILES; ++qt) {
        const int row = qt * 16 + lr;
        const int skb = lk ^ ((row >> 1) & 3);
        short8v bf = *(const short8v*)((const char*)sB + row * 64 + skb * 16);
        float m4[TPW2];
        #pragma unroll
        for (int i = 0; i < TPW2; ++i) {
            float4v c = {0.f, 0.f, 0.f, 0.f};
            c = __builtin_amdgcn_mfma_f32_16x16x32_bf16(af[i], bf, c, 0, 0, 0);
            m4[i] = fmaxf(fmaxf(c[0], c[1]), fmaxf(c[2], c[3]));
        }
        sW[w][qt][lk][lr] = tree_max9(m4);   // flat idx (w*16+qt)*64+l: coalesced
    }
    __syncthreads();

    // Flush: reduce 16 partials (4 waves x 4 lk) per query; ONE pre-checked
    // atomic per (block, query).
    {
        int e = t;                                 // 256 threads = QBLK queries
        int qt = e >> 4, q = e & 15;
        float v = -1e30f;
        #pragma unroll
        for (int ww = 0; ww < 4; ++ww)
            #pragma unroll
            for (int kk = 0; kk < 4; ++kk)
                v = fmaxf(v, sW[ww][qt][kk][q]);
        unsigned u = ford(v);
        unsigned* p = wsmax + qbase + e;
        if (u > *p) atomicMax(p, u);   // monotone: stale read only over-admits
    }
}

// ---------------- pass 2: emit candidates >= max - MARGIN ----------------
__global__ __launch_bounds__(256, 4)
void so3_mfma_cand_kernel(const unsigned short* __restrict__ Ap,
                          const unsigned short* __restrict__ Gp,
                          const unsigned* __restrict__ wsmax,
                          unsigned* __restrict__ cnt,
                          unsigned* __restrict__ cands) {
    __shared__ __align__(16) unsigned short sB[QBLK * 32];   // 16 KB
    __shared__ float sThr[QBLK];                             // 1 KB
    const int t = threadIdx.x, l = t & 63, w = t >> 6;
    const int lr = l & 15, lk = l >> 4;
    const int qbase = blockIdx.y * QBLK;

    stage_A(Ap, sB, t, qbase);
    sThr[t] = funord(wsmax[qbase + t]) - MARGIN;   // thresholds -> LDS, once

    const int tile0 = blockIdx.x * TPB + w * TPW2;
    short8v af[TPW2];
    #pragma unroll
    for (int i = 0; i < TPW2; ++i)
        af[i] = *(const short8v*)(Gp + (size_t)((tile0 + i) * 16 + lr) * 32 + lk * 8);

    __syncthreads();

    for (int qt = 0; qt < QTILES; ++qt) {
        const int row = qt * 16 + lr;                 // this lane's local query
        const float thr = sThr[row];                  // LDS read, uncontended
        const int skb = lk ^ ((row >> 1) & 3);
        short8v bf = *(const short8v*)((const char*)sB + row * 64 + skb * 16);
        #pragma unroll
        for (int i = 0; i < TPW2; ++i) {
            float4v c = {0.f, 0.f, 0.f, 0.f};
            c = __builtin_amdgcn_mfma_f32_16x16x32_bf16(af[i], bf, c, 0, 0, 0);
            float m4 = fmaxf(fmaxf(c[0], c[1]), fmaxf(c[2], c[3]));
            if (m4 >= thr) {                          // rare slow path
                int b = qbase + row;
                #pragma unroll
                for (int r = 0; r < 4; ++r) {
                    if (c[r] >= thr) {
                        int n = (tile0 + i) * 16 + lk * 4 + r;
                        unsigned idx = atomicAdd(cnt, 1u);
                        if (idx < CAP)
                            cands[idx] = ((unsigned)b << 19) | (unsigned)n;
                    }
                }
            }
        }
    }
}

// ---------------- pass 3: exact fp32 rescore of candidates ----------------
__global__ __launch_bounds__(256)
void so3_rescore_kernel(const float* __restrict__ A, const float* __restrict__ G,
                        const unsigned* __restrict__ cnt,
                        const unsigned* __restrict__ cands,
                        unsigned long long* __restrict__ keys) {
    unsigned total = *cnt;
    if (total > CAP) total = CAP;
    const unsigned stride = gridDim.x * 256;
    for (unsigned i = blockIdx.x * 256 + threadIdx.x; i < total; i += stride) {
        unsigned cd = cands[i];
        int b = (int)(cd >> 19), n = (int)(cd & 0x7FFFFu);
        const float* a = A + (size_t)b * 9;
        const float* g = G + (size_t)n * 9;
        // EXACT chain — identical order to reference-matching rounds 2..11
        float d;
        d = a[0] * g[0];
        d = fmaf(a[1], g[1], d);
        d = fmaf(a[2], g[2], d);
        d = fmaf(a[3], g[3], d);
        d = fmaf(a[4], g[4], d);
        d = fmaf(a[5], g[5], d);
        d = fmaf(a[6], g[6], d);
        d = fmaf(a[7], g[7], d);
        d = fmaf(a[8], g[8], d);
        unsigned long long key =
            ((unsigned long long)ford(d) << 32) | (unsigned)(~n);
        unsigned long long seen = keys[b];
        if (key > seen) atomicMax(&keys[b], key);
    }
}

// ---------------- final: unpack + gather ----------------
__global__ __launch_bounds__(256)
void so3_final_kernel(const float* __restrict__ G,
                      const unsigned long long* __restrict__ keys,
                      float* __restrict__ out) {
    int b = blockIdx.x * 256 + threadIdx.x;
    if (b >= B_TOTAL) return;
    unsigned long long key = keys[b];
    unsigned hi = (unsigned)(key >> 32);
    int idx = (int)(~(unsigned)key);
    out[b] = funord(hi);
    const float* g = G + (size_t)idx * 9;
    float* o = out + B_TOTAL + (size_t)b * 9;
    #pragma unroll
    for (int k = 0; k < 9; ++k) o[k] = g[k];
}

// ---------------- fallback (round-5 VALU path, 85.9 us known-good) --------
#define FB_NBLK  2048
#define FB_CHUNK (NGRID / FB_NBLK)
#define FB_NTHR  128
#define FB_BPT   8
__global__ __launch_bounds__(FB_NTHR, 4)
void so3_fb_partial_kernel(const float* __restrict__ A, const float* __restrict__ G,
                           unsigned long long* __restrict__ ws) {
    __shared__ __align__(16) float sG[FB_CHUNK * 12];
    const int t = threadIdx.x;
    const int n0 = blockIdx.x * FB_CHUNK;
    for (int i = t; i < FB_CHUNK * 9; i += FB_NTHR) {
        int row = i / 9, k = i - row * 9;
        sG[row * 12 + k] = G[(size_t)n0 * 9 + i];
    }
    float a[FB_BPT][9];
    #pragma unroll
    for (int j = 0; j < FB_BPT; ++j) {
        const float* ap = A + (size_t)(j * FB_NTHR + t) * 9;
        #pragma unroll
        for (int k = 0; k < 9; ++k) a[j][k] = ap[k];
    }
    float best[FB_BPT]; int bidx[FB_BPT];
    #pragma unroll
    for (int j = 0; j < FB_BPT; ++j) { best[j] = -1e30f; bidx[j] = 0; }
    __syncthreads();
    #pragma unroll 2
    for (int n = 0; n < FB_CHUNK; ++n) {
        const float4* gv = (const float4*)(sG + n * 12);
        const float4 gA = gv[0], gB = gv[1];
        const float g8 = sG[n * 12 + 8];
        const int vn = n0 + n;
        #pragma unroll
        for (int j = 0; j < FB_BPT; ++j) {
            float d;
            d = a[j][0] * gA.x; d = fmaf(a[j][1], gA.y, d); d = fmaf(a[j][2], gA.z, d);
            d = fmaf(a[j][3], gA.w, d); d = fmaf(a[j][4], gB.x, d); d = fmaf(a[j][5], gB.y, d);
            d = fmaf(a[j][6], gB.z, d); d = fmaf(a[j][7], gB.w, d); d = fmaf(a[j][8], g8, d);
            if (d > best[j]) { best[j] = d; bidx[j] = vn; }
        }
    }
    #pragma unroll
    for (int j = 0; j < FB_BPT; ++j) {
        unsigned long long key =
            ((unsigned long long)ford(best[j]) << 32) | (unsigned)(~bidx[j]);
        unsigned long long seen = ws[j * FB_NTHR + t];
        if (key > seen) atomicMax(&ws[j * FB_NTHR + t], key);
    }
}

extern "C" void kernel_launch(void* const* d_in, const int* in_sizes, int n_in,
                              void* d_out, int out_size, void* d_ws, size_t ws_size,
                              hipStream_t stream) {
    const float* A = (const float*)d_in[0];   // rotMat [1024,3,3] fp32
    const float* G = (const float*)d_in[1];   // output_rotmats [294912,3,3] fp32
    float* out = (float*)d_out;
    char* ws = (char*)d_ws;
    unsigned long long* keys = (unsigned long long*)(ws + KEYS_OFF);
    unsigned* wsmax = (unsigned*)(ws + WSMAX_OFF);
    unsigned* cnt   = (unsigned*)(ws + CNT_OFF);
    unsigned* cands = (unsigned*)(ws + CAND_OFF);
    unsigned short* Ap = (unsigned short*)(ws + APACK_OFF);
    unsigned short* Gp = (unsigned short*)(ws + GPACK_OFF);

    if (ws_size < WS_NEED) {   // defensive: unknown ws budget -> proven VALU path
        hipLaunchKernelGGL(so3_init_kernel, dim3(4), dim3(256), 0, stream,
                           keys, wsmax, cnt);
        hipLaunchKernelGGL(so3_fb_partial_kernel, dim3(FB_NBLK), dim3(FB_NTHR),
                           0, stream, A, G, keys);
        hipLaunchKernelGGL(so3_final_kernel, dim3(4), dim3(256), 0, stream,
                           G, keys, out);
        return;
    }

    hipLaunchKernelGGL(so3_init_kernel, dim3(4), dim3(256), 0, stream,
                       keys, wsmax, cnt);
    hipLaunchKernelGGL(so3_pack_kernel, dim3((B_TOTAL * 16) / 256), dim3(256),
                       0, stream, A, (unsigned*)Ap, B_TOTAL, 1);
    hipLaunchKernelGGL(so3_pack_kernel, dim3((NGRID * 16) / 256), dim3(256),
                       0, stream, G, (unsigned*)Gp, NGRID, 0);
    hipLaunchKernelGGL(so3_mfma_max_kernel, dim3(NSLICE, B_TOTAL / QBLK),
                       dim3(256), 0, stream, Ap, Gp, wsmax);
    hipLaunchKernelGGL(so3_mfma_cand_kernel, dim3(NSLICE, B_TOTAL / QBLK),
                       dim3(256), 0, stream, Ap, Gp, wsmax, cnt, cands);
    hipLaunchKernelGGL(so3_rescore_kernel, dim3(128), dim3(256), 0, stream,
                       A, G, cnt, cands, keys);
    hipLaunchKernelGGL(so3_final_kernel, dim3(4), dim3(256), 0, stream,
                       G, keys, out);
}